// Round 17
// baseline (2136.485 us; speedup 1.0000x reference)
//
#include <hip/hip_runtime.h>

#define BT     4096   // B*T rows
#define CDIM   768
#define NLAYER 6
#define NHEAD  12
#define VREAL  50257
#define VPAD   50432  // 197*256

typedef __bf16 bf16x8 __attribute__((ext_vector_type(8)));
typedef float  f32x4  __attribute__((ext_vector_type(4)));

__device__ __forceinline__ unsigned short f2bf(float f) {
    unsigned int u = __builtin_bit_cast(unsigned int, f);
    u += 0x7fffu + ((u >> 16) & 1u);   // round-to-nearest-even
    return (unsigned short)(u >> 16);
}

__device__ __forceinline__ void gload16(const unsigned short* g, unsigned short* l) {
    __builtin_amdgcn_global_load_lds(
        (const __attribute__((address_space(1))) unsigned int*)g,
        (__attribute__((address_space(3))) unsigned int*)l, 16, 0, 0);
}

// Bijective XCD-aware block swizzle (T1): contiguous grid chunk per XCD.
__device__ __forceinline__ void swz_block(int &bx, int &by) {
    int gx = gridDim.x;
    int nwg = gx * gridDim.y;
    if ((nwg & 7) == 0) {
        int lin = by * gx + bx;
        int q = nwg >> 3;
        lin = (lin & 7) * q + (lin >> 3);
        bx = lin % gx;
        by = lin / gx;
    }
}

// ---------------------------------------------------------------------------
// Weight prep: f32 [K][N] (per-layer stacked) -> bf16 [N][K]
// ---------------------------------------------------------------------------
__global__ __launch_bounds__(256) void transpose_conv(
    const float* __restrict__ in, unsigned short* __restrict__ out, int K, int N)
{
    in  += (size_t)blockIdx.z * K * N;
    out += (size_t)blockIdx.z * K * N;
    __shared__ float t[32][33];
    int j0 = blockIdx.x * 32;   // N dim
    int i0 = blockIdx.y * 32;   // K dim
    int c = threadIdx.x;        // 0..31
    int r = threadIdx.y;        // 0..7
    #pragma unroll
    for (int rr = r; rr < 32; rr += 8)
        t[rr][c] = in[(size_t)(i0 + rr) * N + j0 + c];
    __syncthreads();
    #pragma unroll
    for (int rr = r; rr < 32; rr += 8)
        out[(size_t)(j0 + rr) * K + i0 + c] = f2bf(t[c][rr]);
}

// wte f32 [V][C] -> bf16 [VPAD][C] (pad rows zero)
__global__ __launch_bounds__(256) void wteconv(
    const float* __restrict__ wte, unsigned short* __restrict__ out)
{
    size_t e = ((size_t)blockIdx.x * 256 + threadIdx.x) * 4;
    int row = (int)(e / CDIM);
    int col = (int)(e % CDIM);
    ushort4 o;
    if (row < VREAL) {
        float4 v = *(const float4*)(wte + (size_t)row * CDIM + col);
        o.x = f2bf(v.x); o.y = f2bf(v.y); o.z = f2bf(v.z); o.w = f2bf(v.w);
    } else {
        o.x = 0; o.y = 0; o.z = 0; o.w = 0;
    }
    *(ushort4*)(out + e) = o;
}

// x = wte[idx] + wpe[t]
__global__ __launch_bounds__(256) void embed_kernel(
    const int* __restrict__ idx, const float* __restrict__ wte,
    const float* __restrict__ wpe, float* __restrict__ x)
{
    int row = blockIdx.x;           // b*1024 + t
    int t = row & 1023;
    int id = idx[row];
    const float* s = wte + (size_t)id * CDIM;
    const float* p = wpe + (size_t)t * CDIM;
    float* o = x + (size_t)row * CDIM;
    for (int c = threadIdx.x; c < CDIM; c += 256) o[c] = s[c] + p[c];
}

// ---------------------------------------------------------------------------
// LayerNorm: x f32 [4096][768] -> bf16 out (one wave per row), vectorized.
// ---------------------------------------------------------------------------
__global__ __launch_bounds__(256) void ln_kernel(
    const float* __restrict__ x, const float* __restrict__ w,
    const float* __restrict__ b, unsigned short* __restrict__ out)
{
    int row = blockIdx.x * 4 + (threadIdx.x >> 6);
    int lane = threadIdx.x & 63;
    const float* xp = x + (size_t)row * CDIM;
    float4 v[3];
    float s = 0.f, sq = 0.f;
    #pragma unroll
    for (int j = 0; j < 3; ++j) {
        v[j] = *(const float4*)(xp + j * 256 + lane * 4);
        s  += v[j].x + v[j].y + v[j].z + v[j].w;
        sq += v[j].x * v[j].x + v[j].y * v[j].y
            + v[j].z * v[j].z + v[j].w * v[j].w;
    }
    #pragma unroll
    for (int o = 32; o > 0; o >>= 1) {
        s  += __shfl_xor(s, o, 64);
        sq += __shfl_xor(sq, o, 64);
    }
    float mu  = s * (1.f / CDIM);
    float var = sq * (1.f / CDIM) - mu * mu;
    float rs  = rsqrtf(var + 1e-5f);
    unsigned short* op = out + (size_t)row * CDIM;
    #pragma unroll
    for (int j = 0; j < 3; ++j) {
        int c = j * 256 + lane * 4;
        float4 w4 = *(const float4*)(w + c);
        float4 b4 = *(const float4*)(b + c);
        ushort4 o4;
        o4.x = f2bf((v[j].x - mu) * rs * w4.x + b4.x);
        o4.y = f2bf((v[j].y - mu) * rs * w4.y + b4.y);
        o4.z = f2bf((v[j].z - mu) * rs * w4.z + b4.z);
        o4.w = f2bf((v[j].w - mu) * rs * w4.w + b4.w);
        *(ushort4*)(op + c) = o4;
    }
}

// ---------------------------------------------------------------------------
// Unified body GEMM, 64x64 tile, BK=128 as four 32-wide sub-tiles per
// barrier pair (R16 structure — best measured). 32KB LDS, ~5 blocks/CU.
// Deep grids: proj/fc2 768, qkv 2304, fc 3072 blocks (fixes qkv's 576-block
// underfill of the 128-tile version). Swapped mfma operands -> lane regs
// hold 4 consecutive COLUMNS. Ascending-32 K-order (bitwise-stable).
// MODE 1: outF = resid + acc + bias       (f32, float4)
// MODE 2: outB = bf16(gelu(acc+bias))     (ushort4)
// MODE 4: qkv split -> Q[b,h,t,d], K[b,h,t,d] (ushort4), Vt[b,h,d,t]
// ---------------------------------------------------------------------------
template<int MODE>
__global__ __launch_bounds__(256) void gemm64_kernel(
    const unsigned short* __restrict__ A, const unsigned short* __restrict__ Bt,
    const float* __restrict__ bias, const float* __restrict__ resid,
    float* __restrict__ outF, unsigned short* __restrict__ outB,
    unsigned short* __restrict__ qout, unsigned short* __restrict__ kout,
    unsigned short* __restrict__ vtout,
    int K, int Nout)
{
    __shared__ alignas(16) unsigned short As[4][2048];  // [ks][64][32]
    __shared__ alignas(16) unsigned short Bs[4][2048];
    const int tid  = threadIdx.x;
    const int wv   = tid >> 6;
    const int lane = tid & 63;
    const int m0 = blockIdx.x * 64;   // M fastest-varying
    const int n0 = blockIdx.y * 64;
    const int wr = wv >> 1, wc = wv & 1;
    const int srow = lane >> 2;
    const int skk  = (lane & 3) * 8;
    const int fr = lane & 15;
    const int fg = lane >> 4;
    const int fk = fg * 8;

    f32x4 acc[2][2];
    #pragma unroll
    for (int i = 0; i < 2; ++i)
        #pragma unroll
        for (int j = 0; j < 2; ++j) acc[i][j] = f32x4{0.f, 0.f, 0.f, 0.f};

    for (int k0 = 0; k0 < K; k0 += 128) {
        int row = wv * 16 + srow;
        const unsigned short* ga = A  + (size_t)(m0 + row) * K + k0 + skk;
        const unsigned short* gb = Bt + (size_t)(n0 + row) * K + k0 + skk;
        #pragma unroll
        for (int ks = 0; ks < 4; ++ks) {
            gload16(ga + ks * 32, &As[ks][wv * 512]);
            gload16(gb + ks * 32, &Bs[ks][wv * 512]);
        }
        __syncthreads();
        #pragma unroll
        for (int ks = 0; ks < 4; ++ks) {
            bf16x8 a[2], bb[2];
            #pragma unroll
            for (int m = 0; m < 2; ++m)
                a[m] = *(const bf16x8*)&As[ks][(wr * 32 + m * 16 + fr) * 32 + fk];
            #pragma unroll
            for (int n = 0; n < 2; ++n)
                bb[n] = *(const bf16x8*)&Bs[ks][(wc * 32 + n * 16 + fr) * 32 + fk];
            #pragma unroll
            for (int m = 0; m < 2; ++m)
                #pragma unroll
                for (int n = 0; n < 2; ++n)
                    acc[m][n] = __builtin_amdgcn_mfma_f32_16x16x32_bf16(
                        bb[n], a[m], acc[m][n], 0, 0, 0);   // swapped (R11)
        }
        __syncthreads();
    }

    #pragma unroll
    for (int m = 0; m < 2; ++m) {
        int row = m0 + wr * 32 + m * 16 + fr;
        #pragma unroll
        for (int n = 0; n < 2; ++n) {
            int col = n0 + wc * 32 + n * 16 + fg * 4;
            float4 bs = *(const float4*)&bias[col];
            float u0 = acc[m][n][0] + bs.x;
            float u1 = acc[m][n][1] + bs.y;
            float u2 = acc[m][n][2] + bs.z;
            float u3 = acc[m][n][3] + bs.w;
            if (MODE == 1) {
                float4 rs4 = *(const float4*)&resid[(size_t)row * Nout + col];
                float4 o;
                o.x = rs4.x + u0; o.y = rs4.y + u1;
                o.z = rs4.z + u2; o.w = rs4.w + u3;
                *(float4*)&outF[(size_t)row * Nout + col] = o;
            } else if (MODE == 2) {
                ushort4 p;
                p.x = f2bf(0.5f * u0 * (1.f + erff(u0 * 0.70710678118654752f)));
                p.y = f2bf(0.5f * u1 * (1.f + erff(u1 * 0.70710678118654752f)));
                p.z = f2bf(0.5f * u2 * (1.f + erff(u2 * 0.70710678118654752f)));
                p.w = f2bf(0.5f * u3 * (1.f + erff(u3 * 0.70710678118654752f)));
                *(ushort4*)&outB[(size_t)row * Nout + col] = p;
            } else if (MODE == 4) {
                int which = col / 768;
                int hh = (col - which * 768) >> 6;
                int dd = col & 63;          // %4 == 0, dd+3 <= 63 (in-head)
                int bb2 = row >> 10, tt = row & 1023;
                ushort4 v;
                v.x = f2bf(u0); v.y = f2bf(u1); v.z = f2bf(u2); v.w = f2bf(u3);
                if (which == 0)
                    *(ushort4*)&qout[(((size_t)bb2 * NHEAD + hh) * 1024 + tt) * 64 + dd] = v;
                else if (which == 1)
                    *(ushort4*)&kout[(((size_t)bb2 * NHEAD + hh) * 1024 + tt) * 64 + dd] = v;
                else {
                    vtout[(((size_t)bb2 * NHEAD + hh) * 64 + dd + 0) * 1024 + tt] = v.x;
                    vtout[(((size_t)bb2 * NHEAD + hh) * 64 + dd + 1) * 1024 + tt] = v.y;
                    vtout[(((size_t)bb2 * NHEAD + hh) * 64 + dd + 2) * 1024 + tt] = v.z;
                    vtout[(((size_t)bb2 * NHEAD + hh) * 64 + dd + 3) * 1024 + tt] = v.w;
                }
            }
        }
    }
}

// ---------------------------------------------------------------------------
// lm_head GEMM (R12 config — measured floor ~536us). Triple-buffer A-LDS,
// single barrier/tile, 2-deep register B, counted vmcnt(12), z-split M.
// ---------------------------------------------------------------------------
__global__ __launch_bounds__(256, 2) void lmhead_kernel(
    const unsigned short* __restrict__ A, const unsigned short* __restrict__ Bt,
    float* __restrict__ outF)
{
    __shared__ alignas(16) unsigned short ldsA[3][8192];  // [buf][128][64] swizzled
    const int tid  = threadIdx.x;
    const int wv   = tid >> 6;           // 0..3
    const int lane = tid & 63;
    const int fr = lane & 15, fg = lane >> 4;
    int bx = blockIdx.x, by = blockIdx.y;
    swz_block(bx, by);
    const int m0 = blockIdx.z * 2048 + bx * 128;   // M fastest within half
    const int n0 = by * 256;

    const int srow = wv * 8 + (lane >> 3);
    const int sks  = ((lane & 7) * 8) ^ ((lane >> 3) << 3);

    const unsigned short* Bw = Bt + (size_t)(n0 + wv * 64 + fr) * 768 + fg * 8;

    const int swz0 = (fg * 8) ^ ((fr & 7) << 3);        // ks=0
    const int swz1 = (32 + fg * 8) ^ ((fr & 7) << 3);   // ks=1

    f32x4 acc[8][4];
    #pragma unroll
    for (int m = 0; m < 8; ++m)
        #pragma unroll
        for (int n = 0; n < 4; ++n) acc[m][n] = f32x4{0.f, 0.f, 0.f, 0.f};

    bf16x8 brE[4][2], brO[4][2];   // even-tile / odd-tile B fragments

#define LM_STAGE_A(t, buf)                                                    \
    {                                                                         \
        const int k0_ = (t) * 64;                                             \
        _Pragma("unroll")                                                     \
        for (int j = 0; j < 4; ++j)                                           \
            gload16(A + (size_t)(m0 + j * 32 + srow) * 768 + k0_ + sks,       \
                    &ldsA[buf][j * 2048 + wv * 512]);                         \
    }
#define LM_LOAD_B(t, br)                                                      \
    {                                                                         \
        const int k0_ = (t) * 64;                                             \
        _Pragma("unroll")                                                     \
        for (int nf = 0; nf < 4; ++nf) {                                      \
            br[nf][0] = *(const bf16x8*)(Bw + (size_t)nf * 16 * 768 + k0_);   \
            br[nf][1] = *(const bf16x8*)(Bw + (size_t)nf * 16 * 768 + k0_ + 32); \
        }                                                                     \
    }
#define LM_COMPUTE(buf, br)                                                   \
    {                                                                         \
        _Pragma("unroll")                                                     \
        for (int m = 0; m < 8; ++m) {                                         \
            bf16x8 a0 = *(const bf16x8*)&ldsA[buf][(m * 16 + fr) * 64 + swz0];\
            bf16x8 a1 = *(const bf16x8*)&ldsA[buf][(m * 16 + fr) * 64 + swz1];\
            _Pragma("unroll")                                                 \
            for (int nf = 0; nf < 4; ++nf) {                                  \
                acc[m][nf] = __builtin_amdgcn_mfma_f32_16x16x32_bf16(a0, br[nf][0], acc[m][nf], 0, 0, 0); \
                acc[m][nf] = __builtin_amdgcn_mfma_f32_16x16x32_bf16(a1, br[nf][1], acc[m][nf], 0, 0, 0); \
            }                                                                 \
        }                                                                     \
    }
// mid tile t: prefetch t+1 into bufN/brN, wait tile-t residency, 1 barrier, compute
#define LM_TILE(t, bufC, brC, bufN, brN)                                      \
    {                                                                         \
        LM_STAGE_A((t) + 1, bufN);                                            \
        LM_LOAD_B((t) + 1, brN);                                              \
        asm volatile("s_waitcnt vmcnt(12)" ::: "memory");                     \
        __builtin_amdgcn_s_barrier();                                         \
        __builtin_amdgcn_sched_barrier(0);                                    \
        __builtin_amdgcn_s_setprio(1);                                        \
        LM_COMPUTE(bufC, brC);                                                \
        __builtin_amdgcn_s_setprio(0);                                        \
    }
#define LM_TILE_LAST(bufC, brC)                                               \
    {                                                                         \
        asm volatile("s_waitcnt vmcnt(0)" ::: "memory");                      \
        __builtin_amdgcn_s_barrier();                                         \
        __builtin_amdgcn_sched_barrier(0);                                    \
        __builtin_amdgcn_s_setprio(1);                                        \
        LM_COMPUTE(bufC, brC);                                                \
        __builtin_amdgcn_s_setprio(0);                                        \
    }

    LM_STAGE_A(0, 0);
    LM_LOAD_B(0, brE);
    LM_TILE(0,  0, brE, 1, brO);
    LM_TILE(1,  1, brO, 2, brE);
    LM_TILE(2,  2, brE, 0, brO);
    LM_TILE(3,  0, brO, 1, brE);
    LM_TILE(4,  1, brE, 2, brO);
    LM_TILE(5,  2, brO, 0, brE);
    LM_TILE(6,  0, brE, 1, brO);
    LM_TILE(7,  1, brO, 2, brE);
    LM_TILE(8,  2, brE, 0, brO);
    LM_TILE(9,  0, brO, 1, brE);
    LM_TILE(10, 1, brE, 2, brO);
    LM_TILE_LAST(2, brO);
#undef LM_STAGE_A
#undef LM_LOAD_B
#undef LM_COMPUTE
#undef LM_TILE
#undef LM_TILE_LAST

    const int colb = n0 + wv * 64 + fr;
    const int rowb = m0 + fg * 4;
    #pragma unroll
    for (int m = 0; m < 8; ++m) {
        #pragma unroll
        for (int n = 0; n < 4; ++n) {
            int col = colb + n * 16;
            if (col < VREAL) {
                #pragma unroll
                for (int r = 0; r < 4; ++r) {
                    int row = rowb + m * 16 + r;
                    outF[(size_t)row * VREAL + col] = acc[m][n][r];
                }
            }
        }
    }
}

// ---------------------------------------------------------------------------
// MFMA flash attention. Block = (qt, h, b), 4 waves; wave w owns q rows
// qt*64 + w*16 .. +15. K and Vt read from global (L2-resident). P re-layout
// via per-wave LDS. Defer-max (exact): rescale o/l only when max increases.
// ---------------------------------------------------------------------------
__global__ __launch_bounds__(256) void attn_mfma_kernel(
    const unsigned short* __restrict__ qb, const unsigned short* __restrict__ kb,
    const unsigned short* __restrict__ vtb, unsigned short* __restrict__ y)
{
    __shared__ alignas(16) unsigned short Ps[4][16][72];  // per-wave P tile
    const int qt = 15 - blockIdx.x;          // big tiles first
    const int h = blockIdx.y, b = blockIdx.z;
    const int w = threadIdx.x >> 6, lane = threadIdx.x & 63;
    const int fr = lane & 15;                // fragment row index
    const int fg = lane >> 4;                // k-group (0..3)
    const size_t bh = (size_t)(b * NHEAD + h);
    const unsigned short* Qb = qb  + bh * 1024 * 64;
    const unsigned short* Kb = kb  + bh * 1024 * 64;
    const unsigned short* Vt = vtb + bh * 64 * 1024;
    const int q0 = qt * 64 + w * 16;

    bf16x8 aq[2];
    aq[0] = *(const bf16x8*)(Qb + (size_t)(q0 + fr) * 64 + fg * 8);
    aq[1] = *(const bf16x8*)(Qb + (size_t)(q0 + fr) * 64 + 32 + fg * 8);

    f32x4 o[4];
    #pragma unroll
    for (int c = 0; c < 4; ++c) o[c] = f32x4{0.f, 0.f, 0.f, 0.f};
    float m[4], l[4];
    #pragma unroll
    for (int r = 0; r < 4; ++r) { m[r] = -1e30f; l[r] = 0.f; }

    for (int kt = 0; kt <= qt; ++kt) {
        const unsigned short* Kt = Kb + (size_t)kt * 64 * 64;
        // --- S = Q K^T  (acc: q = fg*4+r, kv = c*16+fr) ---
        f32x4 s[4];
        #pragma unroll
        for (int c = 0; c < 4; ++c) {
            bf16x8 bk0 = *(const bf16x8*)(Kt + (size_t)(c * 16 + fr) * 64 + fg * 8);
            bf16x8 bk1 = *(const bf16x8*)(Kt + (size_t)(c * 16 + fr) * 64 + 32 + fg * 8);
            s[c] = f32x4{0.f, 0.f, 0.f, 0.f};
            s[c] = __builtin_amdgcn_mfma_f32_16x16x32_bf16(aq[0], bk0, s[c], 0, 0, 0);
            s[c] = __builtin_amdgcn_mfma_f32_16x16x32_bf16(aq[1], bk1, s[c], 0, 0, 0);
        }
        // --- mask + scale ---
        float sc[4][4];
        #pragma unroll
        for (int c = 0; c < 4; ++c)
            #pragma unroll
            for (int r = 0; r < 4; ++r) {
                float v = s[c][r] * 0.125f;
                if (kt == qt && (kt * 64 + c * 16 + fr) > (q0 + fg * 4 + r))
                    v = -1e30f;
                sc[c][r] = v;
            }
        // --- online softmax (row reduce over 16-lane kv axis) ---
        #pragma unroll
        for (int r = 0; r < 4; ++r) {
            float tm = fmaxf(fmaxf(sc[0][r], sc[1][r]), fmaxf(sc[2][r], sc[3][r]));
            tm = fmaxf(tm, __shfl_xor(tm, 1, 64));
            tm = fmaxf(tm, __shfl_xor(tm, 2, 64));
            tm = fmaxf(tm, __shfl_xor(tm, 4, 64));
            tm = fmaxf(tm, __shfl_xor(tm, 8, 64));
            if (tm > m[r]) {   // defer-max: rescale only on real increase
                float corr = __expf(m[r] - tm);
                m[r] = tm;
                l[r] *= corr;
                #pragma unroll
                for (int c = 0; c < 4; ++c) o[c][r] *= corr;
            }
            float ps = 0.f;
            #pragma unroll
            for (int c = 0; c < 4; ++c) {
                float p = __expf(sc[c][r] - m[r]);
                sc[c][r] = p;
                ps += p;
            }
            ps += __shfl_xor(ps, 1, 64);
            ps += __shfl_xor(ps, 2, 64);
            ps += __shfl_xor(ps, 4, 64);
            ps += __shfl_xor(ps, 8, 64);
            l[r] += ps;
            #pragma unroll
            for (int c = 0; c < 4; ++c)
                Ps[w][fg * 4 + r][c * 16 + fr] = f2bf(sc[c][r]);
        }
        // in-wave LDS write->read ordering (cross-lane, same wave)
        asm volatile("s_waitcnt lgkmcnt(0)" ::: "memory");
        // --- O += P V  (A = P rows, B = Vt rows) ---
        bf16x8 ap0 = *(const bf16x8*)&Ps[w][fr][fg * 8];
        bf16x8 ap1 = *(const bf16x8*)&Ps[w][fr][32 + fg * 8];
        #pragma unroll
        for (int c = 0; c < 4; ++c) {
            const unsigned short* vb = Vt + (size_t)(c * 16 + fr) * 1024 + kt * 64;
            bf16x8 bv0 = *(const bf16x8*)(vb + fg * 8);
            bf16x8 bv1 = *(const bf16x8*)(vb + 32 + fg * 8);
            o[c] = __builtin_amdgcn_mfma_f32_16x16x32_bf16(ap0, bv0, o[c], 0, 0, 0);
            o[c] = __builtin_amdgcn_mfma_f32_16x16x32_bf16(ap1, bv1, o[c], 0, 0, 0);
        }
        asm volatile("s_waitcnt lgkmcnt(0)" ::: "memory");  // done with Ps before next iter
    }

    float inv[4];
    #pragma unroll
    for (int r = 0; r < 4; ++r) inv[r] = 1.f / l[r];
    #pragma unroll
    for (int c = 0; c < 4; ++c)
        #pragma unroll
        for (int r = 0; r < 4; ++r) {
            int q = q0 + fg * 4 + r;
            y[((size_t)(b * 1024 + q)) * CDIM + h * 64 + c * 16 + fr] =
                f2bf(o[c][r] * inv[r]);
        }
}

// ---------------------------------------------------------------------------
extern "C" void kernel_launch(void* const* d_in, const int* in_sizes, int n_in,
                              void* d_out, int out_size, void* d_ws, size_t ws_size,
                              hipStream_t stream) {
    (void)in_sizes; (void)n_in; (void)out_size; (void)ws_size;
    const int*   idx   = (const int*)  d_in[0];
    const float* wte   = (const float*)d_in[1];
    const float* wpe   = (const float*)d_in[2];
    const float* ln1w  = (const float*)d_in[3];
    const float* ln1b  = (const float*)d_in[4];
    const float* attnw = (const float*)d_in[5];
    const float* attnb = (const float*)d_in[6];
    const float* projw = (const float*)d_in[7];
    const float* projb = (const float*)d_in[8];
    const float* ln2w  = (const float*)d_in[9];
    const float* ln2b  = (const float*)d_in[10];
    const float* fcw   = (const float*)d_in[11];
    const float* fcb   = (const float*)d_in[12];
    const float* fc2w  = (const float*)d_in[13];
    const float* fc2b  = (const float*)d_in[14];
    const float* lnfw  = (const float*)d_in[15];
    const float* lnfb  = (const float*)d_in[16];
    float* out = (float*)d_out;

    char* ws = (char*)d_ws;
    size_t off = 0;
    auto alloc = [&](size_t bytes) {
        void* p = ws + off;
        off += (bytes + 255) & ~(size_t)255;
        return p;
    };
    float*          x      = (float*)         alloc((size_t)BT * CDIM * 4);
    unsigned short* hbuf   = (unsigned short*)alloc((size_t)BT * CDIM * 2);
    unsigned short* qbuf   = (unsigned short*)alloc((size_t)BT * CDIM * 2);
    unsigned short* kbuf   = (unsigned short*)alloc((size_t)BT * CDIM * 2);
    unsigned short* vtbuf  = (unsigned short*)alloc((size_t)BT * CDIM * 2);
    unsigned short* ybuf   = (unsigned short*)alloc((size_t)BT * CDIM * 2);
    unsigned short* fcact  = (unsigned short*)alloc((size_t)BT * 4 * CDIM * 2);
    unsigned short* wqkvT  = (unsigned short*)alloc((size_t)NLAYER * 3 * CDIM * CDIM * 2);
    unsigned short* wprojT = (unsigned short*)alloc((size_t)NLAYER * CDIM * CDIM * 2);
    unsigned short* wfcT   = (unsigned short*)alloc((size_t)NLAYER * 4 * CDIM * CDIM * 2);
    unsigned short* wfc2T  = (unsigned short*)alloc((size_t)NLAYER * 4 * CDIM * CDIM * 2);
    unsigned short* wteB   = (unsigned short*)alloc((size_t)VPAD * CDIM * 2);

    // weight prep (re-done every launch: deterministic, ~80us)
    transpose_conv<<<dim3(3*CDIM/32,   CDIM/32, NLAYER), dim3(32,8), 0, stream>>>(attnw, wqkvT, CDIM, 3*CDIM);
    transpose_conv<<<dim3(  CDIM/32,   CDIM/32, NLAYER), dim3(32,8), 0, stream>>>(projw, wprojT, CDIM, CDIM);
    transpose_conv<<<dim3(4*CDIM/32,   CDIM/32, NLAYER), dim3(32,8), 0, stream>>>(fcw,  wfcT,  CDIM, 4*CDIM);
    transpose_conv<<<dim3(  CDIM/32, 4*CDIM/32, NLAYER), dim3(32,8), 0, stream>>>(fc2w, wfc2T, 4*CDIM, CDIM);
    wteconv<<<(VPAD * CDIM / 4) / 256, 256, 0, stream>>>(wte, wteB);
    embed_kernel<<<BT, 256, 0, stream>>>(idx, wte, wpe, x);

    for (int l = 0; l < NLAYER; ++l) {
        ln_kernel<<<BT/4, 256, 0, stream>>>(x, ln1w + l*CDIM, ln1b + l*CDIM, hbuf);
        gemm64_kernel<4><<<dim3(BT/64, 3*CDIM/64), 256, 0, stream>>>(
            hbuf, wqkvT + (size_t)l*3*CDIM*CDIM, attnb + (size_t)l*3*CDIM,
            nullptr, nullptr, nullptr, qbuf, kbuf, vtbuf, CDIM, 3*CDIM);
        attn_mfma_kernel<<<dim3(16, NHEAD, 4), 256, 0, stream>>>(qbuf, kbuf, vtbuf, ybuf);
        gemm64_kernel<1><<<dim3(BT/64, CDIM/64), 256, 0, stream>>>(
            ybuf, wprojT + (size_t)l*CDIM*CDIM, projb + (size_t)l*CDIM,
            x, x, nullptr, nullptr, nullptr, nullptr, CDIM, CDIM);
        ln_kernel<<<BT/4, 256, 0, stream>>>(x, ln2w + l*CDIM, ln2b + l*CDIM, hbuf);
        gemm64_kernel<2><<<dim3(BT/64, 4*CDIM/64), 256, 0, stream>>>(
            hbuf, wfcT + (size_t)l*4*CDIM*CDIM, fcb + (size_t)l*4*CDIM,
            nullptr, nullptr, fcact, nullptr, nullptr, nullptr, CDIM, 4*CDIM);
        gemm64_kernel<1><<<dim3(BT/64, CDIM/64), 256, 0, stream>>>(
            fcact, wfc2T + (size_t)l*4*CDIM*CDIM, fc2b + (size_t)l*CDIM,
            x, x, nullptr, nullptr, nullptr, nullptr, 4*CDIM, CDIM);
    }
    ln_kernel<<<BT/4, 256, 0, stream>>>(x, lnfw, lnfb, hbuf);
    lmhead_kernel<<<dim3(16, VPAD/256, 2), 256, 0, stream>>>(hbuf, wteB, out);
}

// Round 18
// 2039.180 us; speedup vs baseline: 1.0477x; 1.0477x over previous
//
#include <hip/hip_runtime.h>

#define BT     4096   // B*T rows
#define CDIM   768
#define NLAYER 6
#define NHEAD  12
#define VREAL  50257
#define VPAD   50432  // 197*256

typedef __bf16 bf16x8 __attribute__((ext_vector_type(8)));
typedef float  f32x4  __attribute__((ext_vector_type(4)));

__device__ __forceinline__ unsigned short f2bf(float f) {
    unsigned int u = __builtin_bit_cast(unsigned int, f);
    u += 0x7fffu + ((u >> 16) & 1u);   // round-to-nearest-even
    return (unsigned short)(u >> 16);
}

__device__ __forceinline__ void gload16(const unsigned short* g, unsigned short* l) {
    __builtin_amdgcn_global_load_lds(
        (const __attribute__((address_space(1))) unsigned int*)g,
        (__attribute__((address_space(3))) unsigned int*)l, 16, 0, 0);
}

// Bijective XCD-aware block swizzle (T1): contiguous grid chunk per XCD.
__device__ __forceinline__ void swz_block(int &bx, int &by) {
    int gx = gridDim.x;
    int nwg = gx * gridDim.y;
    if ((nwg & 7) == 0) {
        int lin = by * gx + bx;
        int q = nwg >> 3;
        lin = (lin & 7) * q + (lin >> 3);
        bx = lin % gx;
        by = lin / gx;
    }
}

// ---------------------------------------------------------------------------
// Weight prep: f32 [K][N] (per-layer stacked) -> bf16 [N][K]
// ---------------------------------------------------------------------------
__global__ __launch_bounds__(256) void transpose_conv(
    const float* __restrict__ in, unsigned short* __restrict__ out, int K, int N)
{
    in  += (size_t)blockIdx.z * K * N;
    out += (size_t)blockIdx.z * K * N;
    __shared__ float t[32][33];
    int j0 = blockIdx.x * 32;   // N dim
    int i0 = blockIdx.y * 32;   // K dim
    int c = threadIdx.x;        // 0..31
    int r = threadIdx.y;        // 0..7
    #pragma unroll
    for (int rr = r; rr < 32; rr += 8)
        t[rr][c] = in[(size_t)(i0 + rr) * N + j0 + c];
    __syncthreads();
    #pragma unroll
    for (int rr = r; rr < 32; rr += 8)
        out[(size_t)(j0 + rr) * K + i0 + c] = f2bf(t[c][rr]);
}

// wte f32 [V][C] -> bf16 [VPAD][C] (pad rows zero)
__global__ __launch_bounds__(256) void wteconv(
    const float* __restrict__ wte, unsigned short* __restrict__ out)
{
    size_t e = ((size_t)blockIdx.x * 256 + threadIdx.x) * 4;
    int row = (int)(e / CDIM);
    int col = (int)(e % CDIM);
    ushort4 o;
    if (row < VREAL) {
        float4 v = *(const float4*)(wte + (size_t)row * CDIM + col);
        o.x = f2bf(v.x); o.y = f2bf(v.y); o.z = f2bf(v.z); o.w = f2bf(v.w);
    } else {
        o.x = 0; o.y = 0; o.z = 0; o.w = 0;
    }
    *(ushort4*)(out + e) = o;
}

// x = wte[idx] + wpe[t]
__global__ __launch_bounds__(256) void embed_kernel(
    const int* __restrict__ idx, const float* __restrict__ wte,
    const float* __restrict__ wpe, float* __restrict__ x)
{
    int row = blockIdx.x;           // b*1024 + t
    int t = row & 1023;
    int id = idx[row];
    const float* s = wte + (size_t)id * CDIM;
    const float* p = wpe + (size_t)t * CDIM;
    float* o = x + (size_t)row * CDIM;
    for (int c = threadIdx.x; c < CDIM; c += 256) o[c] = s[c] + p[c];
}

// ---------------------------------------------------------------------------
// LayerNorm: x f32 [4096][768] -> bf16 out (one wave per row), vectorized.
// ---------------------------------------------------------------------------
__global__ __launch_bounds__(256) void ln_kernel(
    const float* __restrict__ x, const float* __restrict__ w,
    const float* __restrict__ b, unsigned short* __restrict__ out)
{
    int row = blockIdx.x * 4 + (threadIdx.x >> 6);
    int lane = threadIdx.x & 63;
    const float* xp = x + (size_t)row * CDIM;
    float4 v[3];
    float s = 0.f, sq = 0.f;
    #pragma unroll
    for (int j = 0; j < 3; ++j) {
        v[j] = *(const float4*)(xp + j * 256 + lane * 4);
        s  += v[j].x + v[j].y + v[j].z + v[j].w;
        sq += v[j].x * v[j].x + v[j].y * v[j].y
            + v[j].z * v[j].z + v[j].w * v[j].w;
    }
    #pragma unroll
    for (int o = 32; o > 0; o >>= 1) {
        s  += __shfl_xor(s, o, 64);
        sq += __shfl_xor(sq, o, 64);
    }
    float mu  = s * (1.f / CDIM);
    float var = sq * (1.f / CDIM) - mu * mu;
    float rs  = rsqrtf(var + 1e-5f);
    unsigned short* op = out + (size_t)row * CDIM;
    #pragma unroll
    for (int j = 0; j < 3; ++j) {
        int c = j * 256 + lane * 4;
        float4 w4 = *(const float4*)(w + c);
        float4 b4 = *(const float4*)(b + c);
        ushort4 o4;
        o4.x = f2bf((v[j].x - mu) * rs * w4.x + b4.x);
        o4.y = f2bf((v[j].y - mu) * rs * w4.y + b4.y);
        o4.z = f2bf((v[j].z - mu) * rs * w4.z + b4.z);
        o4.w = f2bf((v[j].w - mu) * rs * w4.w + b4.w);
        *(ushort4*)(op + c) = o4;
    }
}

// ---------------------------------------------------------------------------
// GEMM 128x128 (qkv, fc): single-buffer, BK=64 as two 32-wide sub-tiles per
// barrier pair. High arithmetic intensity (16 MFMA/lane per staged tile) —
// R17 showed 64-tiles halve reuse and lose; this is the measured-best shape
// for N>=2304 grids. Swapped mfma operands -> 4 consecutive COLUMNS/lane.
// MODE 2: outB = bf16(gelu(acc+bias))
// MODE 4: qkv split: acc+bias -> bf16 Q[b,h,t,d], K[b,h,t,d], Vt[b,h,d,t]
// ---------------------------------------------------------------------------
template<int MODE>
__global__ __launch_bounds__(256) void gemm_kernel(
    const unsigned short* __restrict__ A, const unsigned short* __restrict__ Bt,
    const float* __restrict__ bias, const float* __restrict__ resid,
    float* __restrict__ outF, unsigned short* __restrict__ outB,
    unsigned short* __restrict__ qout, unsigned short* __restrict__ kout,
    unsigned short* __restrict__ vtout,
    int K, int Nout)
{
    __shared__ alignas(16) unsigned short As[2][4096];  // [ks][128][32]
    __shared__ alignas(16) unsigned short Bs[2][4096];
    const int tid  = threadIdx.x;
    const int wv   = tid >> 6;
    const int lane = tid & 63;
    const int m0 = blockIdx.x * 128;   // M fastest-varying
    const int n0 = blockIdx.y * 128;
    const int wr = wv >> 1, wc = wv & 1;
    const int srow = lane >> 2;          // staging row within 16-row chunk
    const int skk  = (lane & 3) * 8;     // staging k offset (elements)
    const int fr = lane & 15;            // fragment row/col
    const int fg = lane >> 4;
    const int fk = fg * 8;               // fragment k offset

    f32x4 acc[4][4];
    #pragma unroll
    for (int i = 0; i < 4; ++i)
        #pragma unroll
        for (int j = 0; j < 4; ++j) acc[i][j] = f32x4{0.f, 0.f, 0.f, 0.f};

    for (int k0 = 0; k0 < K; k0 += 64) {
        #pragma unroll
        for (int j = 0; j < 2; ++j) {
            int row = j * 64 + wv * 16 + srow;
            const unsigned short* ga = A  + (size_t)(m0 + row) * K + k0 + skk;
            const unsigned short* gb = Bt + (size_t)(n0 + row) * K + k0 + skk;
            gload16(ga,      &As[0][j * 2048 + wv * 512]);
            gload16(ga + 32, &As[1][j * 2048 + wv * 512]);
            gload16(gb,      &Bs[0][j * 2048 + wv * 512]);
            gload16(gb + 32, &Bs[1][j * 2048 + wv * 512]);
        }
        __syncthreads();
        #pragma unroll
        for (int ks = 0; ks < 2; ++ks) {
            bf16x8 a[4], bb[4];
            #pragma unroll
            for (int m = 0; m < 4; ++m)
                a[m] = *(const bf16x8*)&As[ks][(wr * 64 + m * 16 + fr) * 32 + fk];
            #pragma unroll
            for (int n = 0; n < 4; ++n)
                bb[n] = *(const bf16x8*)&Bs[ks][(wc * 64 + n * 16 + fr) * 32 + fk];
            #pragma unroll
            for (int m = 0; m < 4; ++m)
                #pragma unroll
                for (int n = 0; n < 4; ++n)
                    acc[m][n] = __builtin_amdgcn_mfma_f32_16x16x32_bf16(
                        bb[n], a[m], acc[m][n], 0, 0, 0);   // swapped (R11)
        }
        __syncthreads();
    }

    #pragma unroll
    for (int m = 0; m < 4; ++m) {
        int row = m0 + wr * 64 + m * 16 + fr;
        #pragma unroll
        for (int n = 0; n < 4; ++n) {
            int col = n0 + wc * 64 + n * 16 + fg * 4;
            float4 bs = *(const float4*)&bias[col];
            float u0 = acc[m][n][0] + bs.x;
            float u1 = acc[m][n][1] + bs.y;
            float u2 = acc[m][n][2] + bs.z;
            float u3 = acc[m][n][3] + bs.w;
            if (MODE == 2) {
                ushort4 p;
                p.x = f2bf(0.5f * u0 * (1.f + erff(u0 * 0.70710678118654752f)));
                p.y = f2bf(0.5f * u1 * (1.f + erff(u1 * 0.70710678118654752f)));
                p.z = f2bf(0.5f * u2 * (1.f + erff(u2 * 0.70710678118654752f)));
                p.w = f2bf(0.5f * u3 * (1.f + erff(u3 * 0.70710678118654752f)));
                *(ushort4*)&outB[(size_t)row * Nout + col] = p;
            } else if (MODE == 4) {
                int which = col / 768;
                int hh = (col - which * 768) >> 6;
                int dd = col & 63;          // %4 == 0, dd+3 <= 63 (in-head)
                int bb2 = row >> 10, tt = row & 1023;
                ushort4 v;
                v.x = f2bf(u0); v.y = f2bf(u1); v.z = f2bf(u2); v.w = f2bf(u3);
                if (which == 0)
                    *(ushort4*)&qout[(((size_t)bb2 * NHEAD + hh) * 1024 + tt) * 64 + dd] = v;
                else if (which == 1)
                    *(ushort4*)&kout[(((size_t)bb2 * NHEAD + hh) * 1024 + tt) * 64 + dd] = v;
                else {
                    vtout[(((size_t)bb2 * NHEAD + hh) * 64 + dd + 0) * 1024 + tt] = v.x;
                    vtout[(((size_t)bb2 * NHEAD + hh) * 64 + dd + 1) * 1024 + tt] = v.y;
                    vtout[(((size_t)bb2 * NHEAD + hh) * 64 + dd + 2) * 1024 + tt] = v.z;
                    vtout[(((size_t)bb2 * NHEAD + hh) * 64 + dd + 3) * 1024 + tt] = v.w;
                }
            }
        }
    }
}

// ---------------------------------------------------------------------------
// GEMM 64x64 (proj, fc2 — N=768 grid underfill fix): BK=128 as FOUR 32-wide
// sub-tiles per barrier pair (R16 — best measured). 32KB LDS, 768 blocks.
// outF = resid + acc + bias, float4 epilogue.
// ---------------------------------------------------------------------------
__global__ __launch_bounds__(256) void gemm64_kernel(
    const unsigned short* __restrict__ A, const unsigned short* __restrict__ Bt,
    const float* __restrict__ bias, const float* __restrict__ resid,
    float* __restrict__ outF, int K, int Nout)
{
    __shared__ alignas(16) unsigned short As[4][2048];  // [ks][64][32]
    __shared__ alignas(16) unsigned short Bs[4][2048];
    const int tid  = threadIdx.x;
    const int wv   = tid >> 6;
    const int lane = tid & 63;
    const int m0 = blockIdx.x * 64;   // M fastest-varying
    const int n0 = blockIdx.y * 64;
    const int wr = wv >> 1, wc = wv & 1;
    const int srow = lane >> 2;
    const int skk  = (lane & 3) * 8;
    const int fr = lane & 15;
    const int fg = lane >> 4;
    const int fk = fg * 8;

    f32x4 acc[2][2];
    #pragma unroll
    for (int i = 0; i < 2; ++i)
        #pragma unroll
        for (int j = 0; j < 2; ++j) acc[i][j] = f32x4{0.f, 0.f, 0.f, 0.f};

    for (int k0 = 0; k0 < K; k0 += 128) {
        int row = wv * 16 + srow;
        const unsigned short* ga = A  + (size_t)(m0 + row) * K + k0 + skk;
        const unsigned short* gb = Bt + (size_t)(n0 + row) * K + k0 + skk;
        #pragma unroll
        for (int ks = 0; ks < 4; ++ks) {
            gload16(ga + ks * 32, &As[ks][wv * 512]);
            gload16(gb + ks * 32, &Bs[ks][wv * 512]);
        }
        __syncthreads();
        #pragma unroll
        for (int ks = 0; ks < 4; ++ks) {
            bf16x8 a[2], bb[2];
            #pragma unroll
            for (int m = 0; m < 2; ++m)
                a[m] = *(const bf16x8*)&As[ks][(wr * 32 + m * 16 + fr) * 32 + fk];
            #pragma unroll
            for (int n = 0; n < 2; ++n)
                bb[n] = *(const bf16x8*)&Bs[ks][(wc * 32 + n * 16 + fr) * 32 + fk];
            #pragma unroll
            for (int m = 0; m < 2; ++m)
                #pragma unroll
                for (int n = 0; n < 2; ++n)
                    acc[m][n] = __builtin_amdgcn_mfma_f32_16x16x32_bf16(
                        bb[n], a[m], acc[m][n], 0, 0, 0);   // swapped (R11)
        }
        __syncthreads();
    }

    #pragma unroll
    for (int m = 0; m < 2; ++m) {
        int row = m0 + wr * 32 + m * 16 + fr;
        #pragma unroll
        for (int n = 0; n < 2; ++n) {
            int col = n0 + wc * 32 + n * 16 + fg * 4;
            float4 rs = *(const float4*)&resid[(size_t)row * Nout + col];
            float4 bs = *(const float4*)&bias[col];
            float4 o;
            o.x = rs.x + acc[m][n][0] + bs.x;
            o.y = rs.y + acc[m][n][1] + bs.y;
            o.z = rs.z + acc[m][n][2] + bs.z;
            o.w = rs.w + acc[m][n][3] + bs.w;
            *(float4*)&outF[(size_t)row * Nout + col] = o;
        }
    }
}

// ---------------------------------------------------------------------------
// lm_head GEMM (R12 config — measured floor ~537us). Triple-buffer A-LDS,
// single barrier/tile, 2-deep register B, counted vmcnt(12), z-split M.
// ---------------------------------------------------------------------------
__global__ __launch_bounds__(256, 2) void lmhead_kernel(
    const unsigned short* __restrict__ A, const unsigned short* __restrict__ Bt,
    float* __restrict__ outF)
{
    __shared__ alignas(16) unsigned short ldsA[3][8192];  // [buf][128][64] swizzled
    const int tid  = threadIdx.x;
    const int wv   = tid >> 6;           // 0..3
    const int lane = tid & 63;
    const int fr = lane & 15, fg = lane >> 4;
    int bx = blockIdx.x, by = blockIdx.y;
    swz_block(bx, by);
    const int m0 = blockIdx.z * 2048 + bx * 128;   // M fastest within half
    const int n0 = by * 256;

    const int srow = wv * 8 + (lane >> 3);
    const int sks  = ((lane & 7) * 8) ^ ((lane >> 3) << 3);

    const unsigned short* Bw = Bt + (size_t)(n0 + wv * 64 + fr) * 768 + fg * 8;

    const int swz0 = (fg * 8) ^ ((fr & 7) << 3);        // ks=0
    const int swz1 = (32 + fg * 8) ^ ((fr & 7) << 3);   // ks=1

    f32x4 acc[8][4];
    #pragma unroll
    for (int m = 0; m < 8; ++m)
        #pragma unroll
        for (int n = 0; n < 4; ++n) acc[m][n] = f32x4{0.f, 0.f, 0.f, 0.f};

    bf16x8 brE[4][2], brO[4][2];   // even-tile / odd-tile B fragments

#define LM_STAGE_A(t, buf)                                                    \
    {                                                                         \
        const int k0_ = (t) * 64;                                             \
        _Pragma("unroll")                                                     \
        for (int j = 0; j < 4; ++j)                                           \
            gload16(A + (size_t)(m0 + j * 32 + srow) * 768 + k0_ + sks,       \
                    &ldsA[buf][j * 2048 + wv * 512]);                         \
    }
#define LM_LOAD_B(t, br)                                                      \
    {                                                                         \
        const int k0_ = (t) * 64;                                             \
        _Pragma("unroll")                                                     \
        for (int nf = 0; nf < 4; ++nf) {                                      \
            br[nf][0] = *(const bf16x8*)(Bw + (size_t)nf * 16 * 768 + k0_);   \
            br[nf][1] = *(const bf16x8*)(Bw + (size_t)nf * 16 * 768 + k0_ + 32); \
        }                                                                     \
    }
#define LM_COMPUTE(buf, br)                                                   \
    {                                                                         \
        _Pragma("unroll")                                                     \
        for (int m = 0; m < 8; ++m) {                                         \
            bf16x8 a0 = *(const bf16x8*)&ldsA[buf][(m * 16 + fr) * 64 + swz0];\
            bf16x8 a1 = *(const bf16x8*)&ldsA[buf][(m * 16 + fr) * 64 + swz1];\
            _Pragma("unroll")                                                 \
            for (int nf = 0; nf < 4; ++nf) {                                  \
                acc[m][nf] = __builtin_amdgcn_mfma_f32_16x16x32_bf16(a0, br[nf][0], acc[m][nf], 0, 0, 0); \
                acc[m][nf] = __builtin_amdgcn_mfma_f32_16x16x32_bf16(a1, br[nf][1], acc[m][nf], 0, 0, 0); \
            }                                                                 \
        }                                                                     \
    }
// mid tile t: prefetch t+1 into bufN/brN, wait tile-t residency, 1 barrier, compute
#define LM_TILE(t, bufC, brC, bufN, brN)                                      \
    {                                                                         \
        LM_STAGE_A((t) + 1, bufN);                                            \
        LM_LOAD_B((t) + 1, brN);                                              \
        asm volatile("s_waitcnt vmcnt(12)" ::: "memory");                     \
        __builtin_amdgcn_s_barrier();                                         \
        __builtin_amdgcn_sched_barrier(0);                                    \
        __builtin_amdgcn_s_setprio(1);                                        \
        LM_COMPUTE(bufC, brC);                                                \
        __builtin_amdgcn_s_setprio(0);                                        \
    }
#define LM_TILE_LAST(bufC, brC)                                               \
    {                                                                         \
        asm volatile("s_waitcnt vmcnt(0)" ::: "memory");                      \
        __builtin_amdgcn_s_barrier();                                         \
        __builtin_amdgcn_sched_barrier(0);                                    \
        __builtin_amdgcn_s_setprio(1);                                        \
        LM_COMPUTE(bufC, brC);                                                \
        __builtin_amdgcn_s_setprio(0);                                        \
    }

    LM_STAGE_A(0, 0);
    LM_LOAD_B(0, brE);
    LM_TILE(0,  0, brE, 1, brO);
    LM_TILE(1,  1, brO, 2, brE);
    LM_TILE(2,  2, brE, 0, brO);
    LM_TILE(3,  0, brO, 1, brE);
    LM_TILE(4,  1, brE, 2, brO);
    LM_TILE(5,  2, brO, 0, brE);
    LM_TILE(6,  0, brE, 1, brO);
    LM_TILE(7,  1, brO, 2, brE);
    LM_TILE(8,  2, brE, 0, brO);
    LM_TILE(9,  0, brO, 1, brE);
    LM_TILE(10, 1, brE, 2, brO);
    LM_TILE_LAST(2, brO);
#undef LM_STAGE_A
#undef LM_LOAD_B
#undef LM_COMPUTE
#undef LM_TILE
#undef LM_TILE_LAST

    const int colb = n0 + wv * 64 + fr;
    const int rowb = m0 + fg * 4;
    #pragma unroll
    for (int m = 0; m < 8; ++m) {
        #pragma unroll
        for (int n = 0; n < 4; ++n) {
            int col = colb + n * 16;
            if (col < VREAL) {
                #pragma unroll
                for (int r = 0; r < 4; ++r) {
                    int row = rowb + m * 16 + r;
                    outF[(size_t)row * VREAL + col] = acc[m][n][r];
                }
            }
        }
    }
}

// ---------------------------------------------------------------------------
// MFMA flash attention. Block = (qt, h, b), 4 waves; wave w owns q rows
// qt*64 + w*16 .. +15. K and Vt read from global (L2-resident). P re-layout
// via per-wave LDS. Defer-max (exact): rescale o/l only when max increases.
// ---------------------------------------------------------------------------
__global__ __launch_bounds__(256) void attn_mfma_kernel(
    const unsigned short* __restrict__ qb, const unsigned short* __restrict__ kb,
    const unsigned short* __restrict__ vtb, unsigned short* __restrict__ y)
{
    __shared__ alignas(16) unsigned short Ps[4][16][72];  // per-wave P tile
    const int qt = 15 - blockIdx.x;          // big tiles first
    const int h = blockIdx.y, b = blockIdx.z;
    const int w = threadIdx.x >> 6, lane = threadIdx.x & 63;
    const int fr = lane & 15;                // fragment row index
    const int fg = lane >> 4;                // k-group (0..3)
    const size_t bh = (size_t)(b * NHEAD + h);
    const unsigned short* Qb = qb  + bh * 1024 * 64;
    const unsigned short* Kb = kb  + bh * 1024 * 64;
    const unsigned short* Vt = vtb + bh * 64 * 1024;
    const int q0 = qt * 64 + w * 16;

    bf16x8 aq[2];
    aq[0] = *(const bf16x8*)(Qb + (size_t)(q0 + fr) * 64 + fg * 8);
    aq[1] = *(const bf16x8*)(Qb + (size_t)(q0 + fr) * 64 + 32 + fg * 8);

    f32x4 o[4];
    #pragma unroll
    for (int c = 0; c < 4; ++c) o[c] = f32x4{0.f, 0.f, 0.f, 0.f};
    float m[4], l[4];
    #pragma unroll
    for (int r = 0; r < 4; ++r) { m[r] = -1e30f; l[r] = 0.f; }

    for (int kt = 0; kt <= qt; ++kt) {
        const unsigned short* Kt = Kb + (size_t)kt * 64 * 64;
        // --- S = Q K^T  (acc: q = fg*4+r, kv = c*16+fr) ---
        f32x4 s[4];
        #pragma unroll
        for (int c = 0; c < 4; ++c) {
            bf16x8 bk0 = *(const bf16x8*)(Kt + (size_t)(c * 16 + fr) * 64 + fg * 8);
            bf16x8 bk1 = *(const bf16x8*)(Kt + (size_t)(c * 16 + fr) * 64 + 32 + fg * 8);
            s[c] = f32x4{0.f, 0.f, 0.f, 0.f};
            s[c] = __builtin_amdgcn_mfma_f32_16x16x32_bf16(aq[0], bk0, s[c], 0, 0, 0);
            s[c] = __builtin_amdgcn_mfma_f32_16x16x32_bf16(aq[1], bk1, s[c], 0, 0, 0);
        }
        // --- mask + scale ---
        float sc[4][4];
        #pragma unroll
        for (int c = 0; c < 4; ++c)
            #pragma unroll
            for (int r = 0; r < 4; ++r) {
                float v = s[c][r] * 0.125f;
                if (kt == qt && (kt * 64 + c * 16 + fr) > (q0 + fg * 4 + r))
                    v = -1e30f;
                sc[c][r] = v;
            }
        // --- online softmax (row reduce over 16-lane kv axis) ---
        #pragma unroll
        for (int r = 0; r < 4; ++r) {
            float tm = fmaxf(fmaxf(sc[0][r], sc[1][r]), fmaxf(sc[2][r], sc[3][r]));
            tm = fmaxf(tm, __shfl_xor(tm, 1, 64));
            tm = fmaxf(tm, __shfl_xor(tm, 2, 64));
            tm = fmaxf(tm, __shfl_xor(tm, 4, 64));
            tm = fmaxf(tm, __shfl_xor(tm, 8, 64));
            if (tm > m[r]) {   // defer-max: rescale only on real increase
                float corr = __expf(m[r] - tm);
                m[r] = tm;
                l[r] *= corr;
                #pragma unroll
                for (int c = 0; c < 4; ++c) o[c][r] *= corr;
            }
            float ps = 0.f;
            #pragma unroll
            for (int c = 0; c < 4; ++c) {
                float p = __expf(sc[c][r] - m[r]);
                sc[c][r] = p;
                ps += p;
            }
            ps += __shfl_xor(ps, 1, 64);
            ps += __shfl_xor(ps, 2, 64);
            ps += __shfl_xor(ps, 4, 64);
            ps += __shfl_xor(ps, 8, 64);
            l[r] += ps;
            #pragma unroll
            for (int c = 0; c < 4; ++c)
                Ps[w][fg * 4 + r][c * 16 + fr] = f2bf(sc[c][r]);
        }
        // in-wave LDS write->read ordering (cross-lane, same wave)
        asm volatile("s_waitcnt lgkmcnt(0)" ::: "memory");
        // --- O += P V  (A = P rows, B = Vt rows) ---
        bf16x8 ap0 = *(const bf16x8*)&Ps[w][fr][fg * 8];
        bf16x8 ap1 = *(const bf16x8*)&Ps[w][fr][32 + fg * 8];
        #pragma unroll
        for (int c = 0; c < 4; ++c) {
            const unsigned short* vb = Vt + (size_t)(c * 16 + fr) * 1024 + kt * 64;
            bf16x8 bv0 = *(const bf16x8*)(vb + fg * 8);
            bf16x8 bv1 = *(const bf16x8*)(vb + 32 + fg * 8);
            o[c] = __builtin_amdgcn_mfma_f32_16x16x32_bf16(ap0, bv0, o[c], 0, 0, 0);
            o[c] = __builtin_amdgcn_mfma_f32_16x16x32_bf16(ap1, bv1, o[c], 0, 0, 0);
        }
        asm volatile("s_waitcnt lgkmcnt(0)" ::: "memory");  // done with Ps before next iter
    }

    float inv[4];
    #pragma unroll
    for (int r = 0; r < 4; ++r) inv[r] = 1.f / l[r];
    #pragma unroll
    for (int c = 0; c < 4; ++c)
        #pragma unroll
        for (int r = 0; r < 4; ++r) {
            int q = q0 + fg * 4 + r;
            y[((size_t)(b * 1024 + q)) * CDIM + h * 64 + c * 16 + fr] =
                f2bf(o[c][r] * inv[r]);
        }
}

// ---------------------------------------------------------------------------
extern "C" void kernel_launch(void* const* d_in, const int* in_sizes, int n_in,
                              void* d_out, int out_size, void* d_ws, size_t ws_size,
                              hipStream_t stream) {
    (void)in_sizes; (void)n_in; (void)out_size; (void)ws_size;
    const int*   idx   = (const int*)  d_in[0];
    const float* wte   = (const float*)d_in[1];
    const float* wpe   = (const float*)d_in[2];
    const float* ln1w  = (const float*)d_in[3];
    const float* ln1b  = (const float*)d_in[4];
    const float* attnw = (const float*)d_in[5];
    const float* attnb = (const float*)d_in[6];
    const float* projw = (const float*)d_in[7];
    const float* projb = (const float*)d_in[8];
    const float* ln2w  = (const float*)d_in[9];
    const float* ln2b  = (const float*)d_in[10];
    const float* fcw   = (const float*)d_in[11];
    const float* fcb   = (const float*)d_in[12];
    const float* fc2w  = (const float*)d_in[13];
    const float* fc2b  = (const float*)d_in[14];
    const float* lnfw  = (const float*)d_in[15];
    const float* lnfb  = (const float*)d_in[16];
    float* out = (float*)d_out;

    char* ws = (char*)d_ws;
    size_t off = 0;
    auto alloc = [&](size_t bytes) {
        void* p = ws + off;
        off += (bytes + 255) & ~(size_t)255;
        return p;
    };
    float*          x      = (float*)         alloc((size_t)BT * CDIM * 4);
    unsigned short* hbuf   = (unsigned short*)alloc((size_t)BT * CDIM * 2);
    unsigned short* qbuf   = (unsigned short*)alloc((size_t)BT * CDIM * 2);
    unsigned short* kbuf   = (unsigned short*)alloc((size_t)BT * CDIM * 2);
    unsigned short* vtbuf  = (unsigned short*)alloc((size_t)BT * CDIM * 2);
    unsigned short* ybuf   = (unsigned short*)alloc((size_t)BT * CDIM * 2);
    unsigned short* fcact  = (unsigned short*)alloc((size_t)BT * 4 * CDIM * 2);
    unsigned short* wqkvT  = (unsigned short*)alloc((size_t)NLAYER * 3 * CDIM * CDIM * 2);
    unsigned short* wprojT = (unsigned short*)alloc((size_t)NLAYER * CDIM * CDIM * 2);
    unsigned short* wfcT   = (unsigned short*)alloc((size_t)NLAYER * 4 * CDIM * CDIM * 2);
    unsigned short* wfc2T  = (unsigned short*)alloc((size_t)NLAYER * 4 * CDIM * CDIM * 2);
    unsigned short* wteB   = (unsigned short*)alloc((size_t)VPAD * CDIM * 2);

    // weight prep (re-done every launch: deterministic, ~80us)
    transpose_conv<<<dim3(3*CDIM/32,   CDIM/32, NLAYER), dim3(32,8), 0, stream>>>(attnw, wqkvT, CDIM, 3*CDIM);
    transpose_conv<<<dim3(  CDIM/32,   CDIM/32, NLAYER), dim3(32,8), 0, stream>>>(projw, wprojT, CDIM, CDIM);
    transpose_conv<<<dim3(4*CDIM/32,   CDIM/32, NLAYER), dim3(32,8), 0, stream>>>(fcw,  wfcT,  CDIM, 4*CDIM);
    transpose_conv<<<dim3(  CDIM/32, 4*CDIM/32, NLAYER), dim3(32,8), 0, stream>>>(fc2w, wfc2T, 4*CDIM, CDIM);
    wteconv<<<(VPAD * CDIM / 4) / 256, 256, 0, stream>>>(wte, wteB);
    embed_kernel<<<BT, 256, 0, stream>>>(idx, wte, wpe, x);

    for (int l = 0; l < NLAYER; ++l) {
        ln_kernel<<<BT/4, 256, 0, stream>>>(x, ln1w + l*CDIM, ln1b + l*CDIM, hbuf);
        gemm_kernel<4><<<dim3(BT/128, 3*CDIM/128), 256, 0, stream>>>(
            hbuf, wqkvT + (size_t)l*3*CDIM*CDIM, attnb + (size_t)l*3*CDIM,
            nullptr, nullptr, nullptr, qbuf, kbuf, vtbuf, CDIM, 3*CDIM);
        attn_mfma_kernel<<<dim3(16, NHEAD, 4), 256, 0, stream>>>(qbuf, kbuf, vtbuf, ybuf);
        gemm64_kernel<<<dim3(BT/64, CDIM/64), 256, 0, stream>>>(
            ybuf, wprojT + (size_t)l*CDIM*CDIM, projb + (size_t)l*CDIM,
            x, x, CDIM, CDIM);
        ln_kernel<<<BT/4, 256, 0, stream>>>(x, ln2w + l*CDIM, ln2b + l*CDIM, hbuf);
        gemm_kernel<2><<<dim3(BT/128, 4*CDIM/128), 256, 0, stream>>>(
            hbuf, wfcT + (size_t)l*4*CDIM*CDIM, fcb + (size_t)l*4*CDIM,
            nullptr, nullptr, fcact, nullptr, nullptr, nullptr, CDIM, 4*CDIM);
        gemm64_kernel<<<dim3(BT/64, CDIM/64), 256, 0, stream>>>(
            fcact, wfc2T + (size_t)l*4*CDIM*CDIM, fc2b + (size_t)l*CDIM,
            x, x, 4*CDIM, CDIM);
    }
    ln_kernel<<<BT/4, 256, 0, stream>>>(x, lnfw, lnfb, hbuf);
    lmhead_kernel<<<dim3(16, VPAD/256, 2), 256, 0, stream>>>(hbuf, wteB, out);
}